// Round 15
// baseline (131.983 us; speedup 1.0000x reference)
//
#include <hip/hip_runtime.h>
#include <hip/hip_bf16.h>
#include <math.h>

#define NN 50000
#define DD 128
#define ALPHA 0.1f
#define BETA 0.5f

typedef __attribute__((ext_vector_type(8))) short short8;   // 8x16b MFMA frag
typedef __attribute__((ext_vector_type(4))) float floatx4;  // f32x4 accum
typedef _Float16 h2 __attribute__((ext_vector_type(2)));    // packed f16 pair

__device__ __forceinline__ float bf16lo(unsigned u) {
    return __uint_as_float(u << 16);
}
__device__ __forceinline__ float bf16hi(unsigned u) {
    return __uint_as_float(u & 0xffff0000u);
}
__device__ __forceinline__ unsigned pkh(float a, float b) {
    h2 p = {(_Float16)a, (_Float16)b};
    return __builtin_bit_cast(unsigned, p);
}
__device__ __forceinline__ h2 as_h2(unsigned u) {
    return __builtin_bit_cast(h2, u);
}

// ---------------------------------------------------------------------------
// Kernel 1: prep = rowptr + h->f16 + W->f16 (unchanged, proven).
// ---------------------------------------------------------------------------
__global__ __launch_bounds__(256) void prep_kernel(
    const int* __restrict__ edge_row, int E, int* __restrict__ rp,
    const float* __restrict__ h, ushort* __restrict__ hh,
    const float* __restrict__ W, ushort* __restrict__ wf)
{
    const int t = blockIdx.x * 256 + threadIdx.x;

    if (hh != nullptr && t < NN * DD / 8) {
        const float4 v0 = *reinterpret_cast<const float4*>(h + (size_t)t * 8);
        const float4 v1 = *reinterpret_cast<const float4*>(h + (size_t)t * 8 + 4);
        uint4 o;
        o.x = pkh(v0.x, v0.y);
        o.y = pkh(v0.z, v0.w);
        o.z = pkh(v1.x, v1.y);
        o.w = pkh(v1.z, v1.w);
        *reinterpret_cast<uint4*>(hh + (size_t)t * 8) = o;
    }

    if (wf != nullptr && t < DD * DD / 4) {
        const float4 v = *reinterpret_cast<const float4*>(W + (size_t)t * 4);
        uint2 of;
        of.x = pkh(v.x, v.y);
        of.y = pkh(v.z, v.w);
        *reinterpret_cast<uint2*>(wf + (size_t)t * 4) = of;
    }

    if (t <= E) {
        if (t == 0) {
            int r0 = edge_row[0];
            for (int r = 0; r <= r0; ++r) rp[r] = 0;
        } else if (t == E) {
            int rl = edge_row[E - 1];
            for (int r = rl + 1; r <= NN; ++r) rp[r] = E;
        } else {
            int rprev = edge_row[t - 1];
            int rcur  = edge_row[t];
            for (int r = rprev + 1; r <= rcur; ++r) rp[r] = t;
        }
    }
}

// ---------------------------------------------------------------------------
// Kernel 2: BARRIER-FREE fused agg + MFMA linear + blend.
// 256 thr (4 waves), 8 rows/block; each wave owns rows {2w, 2w+1} END-TO-END:
//   gather (r13's interleaved/unmasked/tail-split loop, 8 gathers in flight)
//   -> per-wave LDS slice (intra-wave in-order, NO __syncthreads)
//   -> full 128-col linear: 8 col-tiles x 4 K-step f16 MFMAs with the 2 rows
//      in A-rows 0..1 (rows 2..15 zeroed; MFMA waste is free, MfmaUtil~1%)
//   -> per-tile epilogue (facc stays 4 regs; peak VGPR ~50 < 64 cap).
// No inter-wave coupling => no barrier skew; waves retire independently.
// C-layout (HW-verified r6): col=lane&15, row=(lane>>4)*4+reg.
// LDS = 4*(2*136*2 + 2*132*4) = 6.4KB/block.
// ---------------------------------------------------------------------------
__global__ __launch_bounds__(256, 8) void fused2r(
    const ushort* __restrict__ hh, const float* __restrict__ h0,
    const int* __restrict__ edge_col, const float* __restrict__ edge_vals,
    const int* __restrict__ rp, const ushort* __restrict__ wf,
    const float* __restrict__ b, const int* __restrict__ lptr,
    float* __restrict__ out)
{
    __shared__ ushort sAf[4][2][136];   // per-wave f16 sup (MFMA A rows 0..1)
    __shared__ float  sSf[4][2][132];   // per-wave fp32 sup (epilogue blend)

    const int tid  = threadIdx.x;
    const int wave = tid >> 6;      // 0..3
    const int lane = tid & 63;
    const int g    = lane >> 4;     // edge slot 0..3
    const int li   = lane & 15;     // feature octet li*8..+7
    const int rA   = blockIdx.x * 8 + wave * 2;
    const int rB   = rA + 1;

    const int lv = *lptr;
    const float theta  = logf(BETA / (float)lv + 1.0f);
    const float mtheta = 1.0f - theta;

    // ---------------- Phase A: 2 rows, interleaved (r13 gather) ----------------
    const int e0A = rp[rA], e1A = rp[rA + 1];
    const int e0B = rp[rB], e1B = rp[rB + 1];

    h2 aA0 = {0, 0}, aA1 = {0, 0}, aA2 = {0, 0}, aA3 = {0, 0};
    h2 aB0 = {0, 0}, aB1 = {0, 0}, aB2 = {0, 0}, aB3 = {0, 0};

    int ebA = e0A, ebB = e0B;
    const int mA = e0A + ((e1A - e0A) & ~15);
    const int mB = e0B + ((e1B - e0B) & ~15);

    for (; ebA < mA && ebB < mB; ebA += 16, ebB += 16) {
        #pragma unroll
        for (int u = 0; u < 4; ++u) {
            const int eA = ebA + u * 4 + g;
            const int cA = edge_col[eA];
            const float vA = edge_vals[eA];
            const uint4 hvA = *reinterpret_cast<const uint4*>(
                hh + (size_t)cA * DD + li * 8);

            const int eB = ebB + u * 4 + g;
            const int cB = edge_col[eB];
            const float vB = edge_vals[eB];
            const uint4 hvB = *reinterpret_cast<const uint4*>(
                hh + (size_t)cB * DD + li * 8);

            const _Float16 vhA = (_Float16)vA;
            const h2 vvA = {vhA, vhA};
            aA0 += as_h2(hvA.x) * vvA;
            aA1 += as_h2(hvA.y) * vvA;
            aA2 += as_h2(hvA.z) * vvA;
            aA3 += as_h2(hvA.w) * vvA;

            const _Float16 vhB = (_Float16)vB;
            const h2 vvB = {vhB, vhB};
            aB0 += as_h2(hvB.x) * vvB;
            aB1 += as_h2(hvB.y) * vvB;
            aB2 += as_h2(hvB.z) * vvB;
            aB3 += as_h2(hvB.w) * vvB;
        }
    }

    for (; ebA < mA; ebA += 16) {
        #pragma unroll
        for (int u = 0; u < 4; ++u) {
            const int eA = ebA + u * 4 + g;
            const int cA = edge_col[eA];
            const float vA = edge_vals[eA];
            const uint4 hvA = *reinterpret_cast<const uint4*>(
                hh + (size_t)cA * DD + li * 8);
            const _Float16 vhA = (_Float16)vA;
            const h2 vvA = {vhA, vhA};
            aA0 += as_h2(hvA.x) * vvA;
            aA1 += as_h2(hvA.y) * vvA;
            aA2 += as_h2(hvA.z) * vvA;
            aA3 += as_h2(hvA.w) * vvA;
        }
    }
    for (; ebB < mB; ebB += 16) {
        #pragma unroll
        for (int u = 0; u < 4; ++u) {
            const int eB = ebB + u * 4 + g;
            const int cB = edge_col[eB];
            const float vB = edge_vals[eB];
            const uint4 hvB = *reinterpret_cast<const uint4*>(
                hh + (size_t)cB * DD + li * 8);
            const _Float16 vhB = (_Float16)vB;
            const h2 vvB = {vhB, vhB};
            aB0 += as_h2(hvB.x) * vvB;
            aB1 += as_h2(hvB.y) * vvB;
            aB2 += as_h2(hvB.z) * vvB;
            aB3 += as_h2(hvB.w) * vvB;
        }
    }

    for (; ebA < e1A; ebA += 4) {
        const int e  = ebA + g;
        const int ee = min(e, e1A - 1);
        const int cA = edge_col[ee];
        const float vA = (e < e1A) ? edge_vals[ee] : 0.0f;
        const uint4 hvA = *reinterpret_cast<const uint4*>(
            hh + (size_t)cA * DD + li * 8);
        const _Float16 vhA = (_Float16)vA;
        const h2 vvA = {vhA, vhA};
        aA0 += as_h2(hvA.x) * vvA;
        aA1 += as_h2(hvA.y) * vvA;
        aA2 += as_h2(hvA.z) * vvA;
        aA3 += as_h2(hvA.w) * vvA;
    }
    for (; ebB < e1B; ebB += 4) {
        const int e  = ebB + g;
        const int ee = min(e, e1B - 1);
        const int cB = edge_col[ee];
        const float vB = (e < e1B) ? edge_vals[ee] : 0.0f;
        const uint4 hvB = *reinterpret_cast<const uint4*>(
            hh + (size_t)cB * DD + li * 8);
        const _Float16 vhB = (_Float16)vB;
        const h2 vvB = {vhB, vhB};
        aB0 += as_h2(hvB.x) * vvB;
        aB1 += as_h2(hvB.y) * vvB;
        aB2 += as_h2(hvB.z) * vvB;
        aB3 += as_h2(hvB.w) * vvB;
    }

    float accA[8], accB[8];
    accA[0] = (float)aA0.x; accA[1] = (float)aA0.y;
    accA[2] = (float)aA1.x; accA[3] = (float)aA1.y;
    accA[4] = (float)aA2.x; accA[5] = (float)aA2.y;
    accA[6] = (float)aA3.x; accA[7] = (float)aA3.y;
    accB[0] = (float)aB0.x; accB[1] = (float)aB0.y;
    accB[2] = (float)aB1.x; accB[3] = (float)aB1.y;
    accB[4] = (float)aB2.x; accB[5] = (float)aB2.y;
    accB[6] = (float)aB3.x; accB[7] = (float)aB3.y;

    #pragma unroll
    for (int j = 0; j < 8; ++j) {
        accA[j] += __shfl_xor(accA[j], 16);
        accA[j] += __shfl_xor(accA[j], 32);
        accB[j] += __shfl_xor(accB[j], 16);
        accB[j] += __shfl_xor(accB[j], 32);
    }

    // blend + stage into this wave's private LDS slice (lanes 0..15)
    if (g == 0) {
        {
            const float4 h0a = *reinterpret_cast<const float4*>(
                h0 + (size_t)rA * DD + li * 8);
            const float4 h0b = *reinterpret_cast<const float4*>(
                h0 + (size_t)rA * DD + li * 8 + 4);
            float s0 = fmaf(1.0f - ALPHA, accA[0], ALPHA * h0a.x);
            float s1 = fmaf(1.0f - ALPHA, accA[1], ALPHA * h0a.y);
            float s2 = fmaf(1.0f - ALPHA, accA[2], ALPHA * h0a.z);
            float s3 = fmaf(1.0f - ALPHA, accA[3], ALPHA * h0a.w);
            float s4 = fmaf(1.0f - ALPHA, accA[4], ALPHA * h0b.x);
            float s5 = fmaf(1.0f - ALPHA, accA[5], ALPHA * h0b.y);
            float s6 = fmaf(1.0f - ALPHA, accA[6], ALPHA * h0b.z);
            float s7 = fmaf(1.0f - ALPHA, accA[7], ALPHA * h0b.w);
            *reinterpret_cast<float4*>(&sSf[wave][0][li * 8]) =
                make_float4(s0, s1, s2, s3);
            *reinterpret_cast<float4*>(&sSf[wave][0][li * 8 + 4]) =
                make_float4(s4, s5, s6, s7);
            uint4 pk;
            pk.x = pkh(s0, s1);
            pk.y = pkh(s2, s3);
            pk.z = pkh(s4, s5);
            pk.w = pkh(s6, s7);
            *reinterpret_cast<uint4*>(&sAf[wave][0][li * 8]) = pk;
        }
        {
            const float4 h0a = *reinterpret_cast<const float4*>(
                h0 + (size_t)rB * DD + li * 8);
            const float4 h0b = *reinterpret_cast<const float4*>(
                h0 + (size_t)rB * DD + li * 8 + 4);
            float s0 = fmaf(1.0f - ALPHA, accB[0], ALPHA * h0a.x);
            float s1 = fmaf(1.0f - ALPHA, accB[1], ALPHA * h0a.y);
            float s2 = fmaf(1.0f - ALPHA, accB[2], ALPHA * h0a.z);
            float s3 = fmaf(1.0f - ALPHA, accB[3], ALPHA * h0a.w);
            float s4 = fmaf(1.0f - ALPHA, accB[4], ALPHA * h0b.x);
            float s5 = fmaf(1.0f - ALPHA, accB[5], ALPHA * h0b.y);
            float s6 = fmaf(1.0f - ALPHA, accB[6], ALPHA * h0b.z);
            float s7 = fmaf(1.0f - ALPHA, accB[7], ALPHA * h0b.w);
            *reinterpret_cast<float4*>(&sSf[wave][1][li * 8]) =
                make_float4(s0, s1, s2, s3);
            *reinterpret_cast<float4*>(&sSf[wave][1][li * 8 + 4]) =
                make_float4(s4, s5, s6, s7);
            uint4 pk;
            pk.x = pkh(s0, s1);
            pk.y = pkh(s2, s3);
            pk.z = pkh(s4, s5);
            pk.w = pkh(s6, s7);
            *reinterpret_cast<uint4*>(&sAf[wave][1][li * 8]) = pk;
        }
    }
    // intra-wave LDS is processed in order for a wave; fence the compiler only
    __builtin_amdgcn_wave_barrier();

    // ---------------- Phase B: this wave's 2 rows x all 128 cols ----------------
    const int la = lane & 15;
    const int k0 = (lane >> 4) * 8;
    const int rowsel = min(la, 1);          // A-row source (rows >=2 zeroed)
    const bool valid = (la < 2);

    // preload the 4 A-frags (one per K step)
    short8 af[4];
    #pragma unroll
    for (int s = 0; s < 4; ++s) {
        const short8 v = *reinterpret_cast<const short8*>(
            &sAf[wave][rowsel][s * 32 + k0]);
        af[s] = valid ? v : (short8){0, 0, 0, 0, 0, 0, 0, 0};
    }

    const int rg = (lane >> 4) * 4;         // C-row group base
    #pragma unroll
    for (int t = 0; t < 8; ++t) {
        const int c = t * 16 + la;
        floatx4 facc = (floatx4){0.f, 0.f, 0.f, 0.f};
        #pragma unroll
        for (int s = 0; s < 4; ++s) {
            const short8 bf = *reinterpret_cast<const short8*>(
                wf + (size_t)c * DD + s * 32 + k0);
            facc = __builtin_amdgcn_mfma_f32_16x16x32_f16(af[s], bf, facc, 0, 0, 0);
        }
        // epilogue: only C rows 0,1 are real; they live in lanes with rg==0
        if (rg == 0) {
            const float bb = b[c];
            out[(size_t)rA * DD + c] =
                theta * (facc[0] + bb) + mtheta * sSf[wave][0][c];
            out[(size_t)rB * DD + c] =
                theta * (facc[1] + bb) + mtheta * sSf[wave][1][c];
        }
    }
}

// ---------------------------------------------------------------------------
// Tier0 fallback (ws too small): fp32 aggregation + fp32-vector linear.
// ---------------------------------------------------------------------------
__global__ __launch_bounds__(256, 6) void agg_fp32(
    const float* __restrict__ h, const float* __restrict__ h0,
    const int* __restrict__ edge_col, const float* __restrict__ edge_vals,
    const int* __restrict__ rp, float* __restrict__ io)
{
    const int wave = threadIdx.x >> 6;
    const int lane = threadIdx.x & 63;
    const int p    = lane >> 5;
    const int li   = lane & 31;
    const int r    = blockIdx.x * 4 + wave;
    if (r >= NN) return;

    const int e0 = rp[r], e1 = rp[r + 1];

    float4 A[4];
    #pragma unroll
    for (int u = 0; u < 4; ++u) A[u] = make_float4(0.f, 0.f, 0.f, 0.f);

    for (int eb = e0; eb < e1; eb += 8) {
        #pragma unroll
        for (int u = 0; u < 4; ++u) {
            const int e  = eb + 2 * u + p;
            const int ee = min(e, e1 - 1);
            const int   c = edge_col[ee];
            const float v = (e < e1) ? edge_vals[ee] : 0.0f;
            const float4 hv =
                *reinterpret_cast<const float4*>(h + (size_t)c * DD + li * 4);
            A[u].x = fmaf(v, hv.x, A[u].x);
            A[u].y = fmaf(v, hv.y, A[u].y);
            A[u].z = fmaf(v, hv.z, A[u].z);
            A[u].w = fmaf(v, hv.w, A[u].w);
        }
    }
    float4 s;
    s.x = (A[0].x + A[1].x) + (A[2].x + A[3].x);
    s.y = (A[0].y + A[1].y) + (A[2].y + A[3].y);
    s.z = (A[0].z + A[1].z) + (A[2].z + A[3].z);
    s.w = (A[0].w + A[1].w) + (A[2].w + A[3].w);
    s.x += __shfl_xor(s.x, 32);
    s.y += __shfl_xor(s.y, 32);
    s.z += __shfl_xor(s.z, 32);
    s.w += __shfl_xor(s.w, 32);

    if (p == 0) {
        const float4 h0v =
            *reinterpret_cast<const float4*>(h0 + (size_t)r * DD + li * 4);
        float4 sup;
        sup.x = fmaf(1.0f - ALPHA, s.x, ALPHA * h0v.x);
        sup.y = fmaf(1.0f - ALPHA, s.y, ALPHA * h0v.y);
        sup.z = fmaf(1.0f - ALPHA, s.z, ALPHA * h0v.z);
        sup.w = fmaf(1.0f - ALPHA, s.w, ALPHA * h0v.w);
        *reinterpret_cast<float4*>(io + (size_t)r * DD + li * 4) = sup;
    }
}

#define RPB 64
#define SPAD 132
#define WPAD 136

__global__ __launch_bounds__(512, 4) void lin_kernel(
    float* io, const float* __restrict__ W, const float* __restrict__ b,
    const int* __restrict__ lptr)
{
    __shared__ float sS[RPB][SPAD];
    __shared__ __hip_bfloat16 sWt[DD][WPAD];

    const int tid = threadIdx.x;
    const int r0  = blockIdx.x * RPB;
    const int tr  = tid >> 4;
    const int tc  = tid & 15;

    const int lv = *lptr;
    const float theta  = logf(BETA / (float)lv + 1.0f);
    const float mtheta = 1.0f - theta;

    for (int i = tid * 4; i < DD * DD; i += 512 * 4) {
        const float4 w4 = *reinterpret_cast<const float4*>(W + i);
        const int o = i >> 7;
        const int k = i & 127;
        sWt[k + 0][o] = __float2bfloat16(w4.x);
        sWt[k + 1][o] = __float2bfloat16(w4.y);
        sWt[k + 2][o] = __float2bfloat16(w4.z);
        sWt[k + 3][o] = __float2bfloat16(w4.w);
    }

    for (int idx = tid; idx < RPB * 32; idx += 512) {
        const int row = idx >> 5;
        const int q   = idx & 31;
        const int rr  = r0 + row;
        const float4 v = (rr < NN)
            ? *reinterpret_cast<const float4*>(io + (size_t)rr * DD + q * 4)
            : make_float4(0.f, 0.f, 0.f, 0.f);
        *reinterpret_cast<float4*>(&sS[row][q * 4]) = v;
    }
    __syncthreads();

    float acc[2][8];
    #pragma unroll
    for (int i = 0; i < 2; ++i)
        #pragma unroll
        for (int j = 0; j < 8; ++j) acc[i][j] = 0.f;

    for (int k = 0; k < DD; k += 4) {
        const float4 a0 = *reinterpret_cast<const float4*>(&sS[tr * 2 + 0][k]);
        const float4 a1 = *reinterpret_cast<const float4*>(&sS[tr * 2 + 1][k]);
        const float aa0[4] = {a0.x, a0.y, a0.z, a0.w};
        const float aa1[4] = {a1.x, a1.y, a1.z, a1.w};
        #pragma unroll
        for (int kk = 0; kk < 4; ++kk) {
            const uint4 wr = *reinterpret_cast<const uint4*>(&sWt[k + kk][tc * 8]);
            float w[8];
            w[0] = bf16lo(wr.x); w[1] = bf16hi(wr.x);
            w[2] = bf16lo(wr.y); w[3] = bf16hi(wr.y);
            w[4] = bf16lo(wr.z); w[5] = bf16hi(wr.z);
            w[6] = bf16lo(wr.w); w[7] = bf16hi(wr.w);
            #pragma unroll
            for (int j = 0; j < 8; ++j) {
                acc[0][j] = fmaf(aa0[kk], w[j], acc[0][j]);
                acc[1][j] = fmaf(aa1[kk], w[j], acc[1][j]);
            }
        }
    }

    #pragma unroll
    for (int i = 0; i < 2; ++i) {
        const int ri = tr * 2 + i;
        const int rr = r0 + ri;
        if (rr >= NN) continue;
        #pragma unroll
        for (int j4 = 0; j4 < 2; ++j4) {
            const int cc = tc * 8 + j4 * 4;
            const float4 bv  = *reinterpret_cast<const float4*>(&b[cc]);
            const float4 sup = *reinterpret_cast<const float4*>(&sS[ri][cc]);
            float4 o4;
            o4.x = theta * (acc[i][j4 * 4 + 0] + bv.x) + mtheta * sup.x;
            o4.y = theta * (acc[i][j4 * 4 + 1] + bv.y) + mtheta * sup.y;
            o4.z = theta * (acc[i][j4 * 4 + 2] + bv.z) + mtheta * sup.z;
            o4.w = theta * (acc[i][j4 * 4 + 3] + bv.w) + mtheta * sup.w;
            *reinterpret_cast<float4*>(io + (size_t)rr * DD + cc) = o4;
        }
    }
}

extern "C" void kernel_launch(void* const* d_in, const int* in_sizes, int n_in,
                              void* d_out, int out_size, void* d_ws, size_t ws_size,
                              hipStream_t stream) {
    const float* h         = (const float*)d_in[0];
    const float* h0        = (const float*)d_in[1];
    const int*   edge_row  = (const int*)d_in[2];
    const int*   edge_col  = (const int*)d_in[3];
    const float* edge_vals = (const float*)d_in[4];
    const float* W         = (const float*)d_in[5];
    const float* b         = (const float*)d_in[6];
    const int*   lptr      = (const int*)d_in[7];
    const int E = in_sizes[2];

    // ws layout: rp (256KB) | hh f16 h (12.8MB) | wf f16 W (32KB)
    char* wsb = (char*)d_ws;
    const size_t sz_hh = (size_t)NN * DD * sizeof(ushort);
    const size_t sz_w  = (size_t)DD * DD * sizeof(ushort);
    int*    rp = (int*)wsb;
    ushort* hh = (ushort*)(wsb + (1 << 18));
    ushort* wf = (ushort*)(wsb + (1 << 18) + sz_hh);
    float*  io = (float*)d_out;

    const size_t need = (size_t)(1 << 18) + sz_hh + sz_w;

    const int nT = (NN * DD / 8 > E + 1) ? NN * DD / 8 : E + 1;
    const int gridP = (nT + 255) / 256;

    if (ws_size >= need) {
        prep_kernel<<<gridP, 256, 0, stream>>>(edge_row, E, rp, h, hh, W, wf);
        fused2r<<<(NN + 7) / 8, 256, 0, stream>>>(
            hh, h0, edge_col, edge_vals, rp, wf, b, lptr, io);
    } else {
        prep_kernel<<<gridP, 256, 0, stream>>>(edge_row, E, rp, h,
                                               nullptr, W, nullptr);
        agg_fp32<<<(NN + 3) / 4, 256, 0, stream>>>(h, h0, edge_col, edge_vals, rp, io);
        lin_kernel<<<(NN + RPB - 1) / RPB, 512, 0, stream>>>(io, W, b, lptr);
    }
}

// Round 16
// 62.998 us; speedup vs baseline: 2.0950x; 2.0950x over previous
//
#include <hip/hip_runtime.h>
#include <hip/hip_bf16.h>
#include <math.h>

#define NN 50000
#define DD 128
#define ALPHA 0.1f
#define BETA 0.5f

typedef __attribute__((ext_vector_type(8))) short short8;   // 8x16b MFMA frag
typedef __attribute__((ext_vector_type(4))) float floatx4;  // f32x4 accum
typedef _Float16 h2 __attribute__((ext_vector_type(2)));    // packed f16 pair

__device__ __forceinline__ float bf16lo(unsigned u) {
    return __uint_as_float(u << 16);
}
__device__ __forceinline__ float bf16hi(unsigned u) {
    return __uint_as_float(u & 0xffff0000u);
}
__device__ __forceinline__ unsigned pkh(float a, float b) {
    h2 p = {(_Float16)a, (_Float16)b};
    return __builtin_bit_cast(unsigned, p);
}
__device__ __forceinline__ h2 as_h2(unsigned u) {
    return __builtin_bit_cast(h2, u);
}

// ---------------------------------------------------------------------------
// Kernel 1: prep = rowptr + h->f16 + W->f16.
// ---------------------------------------------------------------------------
__global__ __launch_bounds__(256) void prep_kernel(
    const int* __restrict__ edge_row, int E, int* __restrict__ rp,
    const float* __restrict__ h, ushort* __restrict__ hh,
    const float* __restrict__ W, ushort* __restrict__ wf)
{
    const int t = blockIdx.x * 256 + threadIdx.x;

    if (hh != nullptr && t < NN * DD / 8) {
        const float4 v0 = *reinterpret_cast<const float4*>(h + (size_t)t * 8);
        const float4 v1 = *reinterpret_cast<const float4*>(h + (size_t)t * 8 + 4);
        uint4 o;
        o.x = pkh(v0.x, v0.y);
        o.y = pkh(v0.z, v0.w);
        o.z = pkh(v1.x, v1.y);
        o.w = pkh(v1.z, v1.w);
        *reinterpret_cast<uint4*>(hh + (size_t)t * 8) = o;
    }

    if (wf != nullptr && t < DD * DD / 4) {
        const float4 v = *reinterpret_cast<const float4*>(W + (size_t)t * 4);
        uint2 of;
        of.x = pkh(v.x, v.y);
        of.y = pkh(v.z, v.w);
        *reinterpret_cast<uint2*>(wf + (size_t)t * 4) = of;
    }

    if (t <= E) {
        if (t == 0) {
            int r0 = edge_row[0];
            for (int r = 0; r <= r0; ++r) rp[r] = 0;
        } else if (t == E) {
            int rl = edge_row[E - 1];
            for (int r = rl + 1; r <= NN; ++r) rp[r] = E;
        } else {
            int rprev = edge_row[t - 1];
            int rcur  = edge_row[t];
            for (int r = rprev + 1; r <= rcur; ++r) rp[r] = t;
        }
    }
}

// ---------------------------------------------------------------------------
// Kernel 2: FUSED agg + MFMA linear + blend. 16 rows/block, 512 thr (8 waves).
// Phase A: wave w aggregates rows 2w, 2w+1. Edge loop split to kill tail
//   waste: (a) joint interleaved UNMASKED full-16 chunks (8 gathers in
//   flight), (b) per-row drain of full chunks, (c) remainder in 4-edge
//   masked steps. Barrier. Phase B: 8 waves, one 16-col tile each
//   (4 K-step f16 MFMAs, B straight from L2-hot wf).
// C-layout (HW-verified r6): col=lane&15, row=(lane>>4)*4+reg.
// LDS = 4.4KB; launch_bounds(512,8) -> VGPR<=64.
// BEST-KNOWN CONFIG (round 13: 63.2us total, fused8w 56us, no spill).
// ---------------------------------------------------------------------------
__global__ __launch_bounds__(512, 8) void fused8w(
    const ushort* __restrict__ hh, const float* __restrict__ h0,
    const int* __restrict__ edge_col, const float* __restrict__ edge_vals,
    const int* __restrict__ rp, const ushort* __restrict__ wf,
    const float* __restrict__ b, const int* __restrict__ lptr,
    float* __restrict__ out)
{
    __shared__ ushort sA[16][136];

    const int tid  = threadIdx.x;
    const int wave = tid >> 6;      // 0..7
    const int lane = tid & 63;
    const int g    = lane >> 4;     // edge slot 0..3
    const int li   = lane & 15;     // feature octet li*8..+7
    const int r0   = blockIdx.x * 16;
    const int rA   = r0 + wave * 2;
    const int rB   = rA + 1;

    const int lv = *lptr;
    const float theta  = logf(BETA / (float)lv + 1.0f);
    const float mtheta = 1.0f - theta;

    // ---------------- Phase A ----------------
    const int e0A = rp[rA], e1A = rp[rA + 1];
    const int e0B = rp[rB], e1B = rp[rB + 1];

    h2 aA0 = {0, 0}, aA1 = {0, 0}, aA2 = {0, 0}, aA3 = {0, 0};
    h2 aB0 = {0, 0}, aB1 = {0, 0}, aB2 = {0, 0}, aB3 = {0, 0};

    int ebA = e0A, ebB = e0B;
    const int mA = e0A + ((e1A - e0A) & ~15);   // end of full-16 chunks, row A
    const int mB = e0B + ((e1B - e0B) & ~15);   // end of full-16 chunks, row B

    // (a) joint interleaved full chunks — unmasked, 8 gathers in flight
    for (; ebA < mA && ebB < mB; ebA += 16, ebB += 16) {
        #pragma unroll
        for (int u = 0; u < 4; ++u) {
            const int eA = ebA + u * 4 + g;
            const int cA = edge_col[eA];
            const float vA = edge_vals[eA];
            const uint4 hvA = *reinterpret_cast<const uint4*>(
                hh + (size_t)cA * DD + li * 8);

            const int eB = ebB + u * 4 + g;
            const int cB = edge_col[eB];
            const float vB = edge_vals[eB];
            const uint4 hvB = *reinterpret_cast<const uint4*>(
                hh + (size_t)cB * DD + li * 8);

            const _Float16 vhA = (_Float16)vA;
            const h2 vvA = {vhA, vhA};
            aA0 += as_h2(hvA.x) * vvA;
            aA1 += as_h2(hvA.y) * vvA;
            aA2 += as_h2(hvA.z) * vvA;
            aA3 += as_h2(hvA.w) * vvA;

            const _Float16 vhB = (_Float16)vB;
            const h2 vvB = {vhB, vhB};
            aB0 += as_h2(hvB.x) * vvB;
            aB1 += as_h2(hvB.y) * vvB;
            aB2 += as_h2(hvB.z) * vvB;
            aB3 += as_h2(hvB.w) * vvB;
        }
    }

    // (b) drain leftover full chunks — unmasked
    for (; ebA < mA; ebA += 16) {
        #pragma unroll
        for (int u = 0; u < 4; ++u) {
            const int eA = ebA + u * 4 + g;
            const int cA = edge_col[eA];
            const float vA = edge_vals[eA];
            const uint4 hvA = *reinterpret_cast<const uint4*>(
                hh + (size_t)cA * DD + li * 8);
            const _Float16 vhA = (_Float16)vA;
            const h2 vvA = {vhA, vhA};
            aA0 += as_h2(hvA.x) * vvA;
            aA1 += as_h2(hvA.y) * vvA;
            aA2 += as_h2(hvA.z) * vvA;
            aA3 += as_h2(hvA.w) * vvA;
        }
    }
    for (; ebB < mB; ebB += 16) {
        #pragma unroll
        for (int u = 0; u < 4; ++u) {
            const int eB = ebB + u * 4 + g;
            const int cB = edge_col[eB];
            const float vB = edge_vals[eB];
            const uint4 hvB = *reinterpret_cast<const uint4*>(
                hh + (size_t)cB * DD + li * 8);
            const _Float16 vhB = (_Float16)vB;
            const h2 vvB = {vhB, vhB};
            aB0 += as_h2(hvB.x) * vvB;
            aB1 += as_h2(hvB.y) * vvB;
            aB2 += as_h2(hvB.z) * vvB;
            aB3 += as_h2(hvB.w) * vvB;
        }
    }

    // (c) remainders: 4-edge masked steps (<=3 wasted slots each)
    for (; ebA < e1A; ebA += 4) {
        const int e  = ebA + g;
        const int ee = min(e, e1A - 1);
        const int cA = edge_col[ee];
        const float vA = (e < e1A) ? edge_vals[ee] : 0.0f;
        const uint4 hvA = *reinterpret_cast<const uint4*>(
            hh + (size_t)cA * DD + li * 8);
        const _Float16 vhA = (_Float16)vA;
        const h2 vvA = {vhA, vhA};
        aA0 += as_h2(hvA.x) * vvA;
        aA1 += as_h2(hvA.y) * vvA;
        aA2 += as_h2(hvA.z) * vvA;
        aA3 += as_h2(hvA.w) * vvA;
    }
    for (; ebB < e1B; ebB += 4) {
        const int e  = ebB + g;
        const int ee = min(e, e1B - 1);
        const int cB = edge_col[ee];
        const float vB = (e < e1B) ? edge_vals[ee] : 0.0f;
        const uint4 hvB = *reinterpret_cast<const uint4*>(
            hh + (size_t)cB * DD + li * 8);
        const _Float16 vhB = (_Float16)vB;
        const h2 vvB = {vhB, vhB};
        aB0 += as_h2(hvB.x) * vvB;
        aB1 += as_h2(hvB.y) * vvB;
        aB2 += as_h2(hvB.z) * vvB;
        aB3 += as_h2(hvB.w) * vvB;
    }

    float accA[8], accB[8];
    accA[0] = (float)aA0.x; accA[1] = (float)aA0.y;
    accA[2] = (float)aA1.x; accA[3] = (float)aA1.y;
    accA[4] = (float)aA2.x; accA[5] = (float)aA2.y;
    accA[6] = (float)aA3.x; accA[7] = (float)aA3.y;
    accB[0] = (float)aB0.x; accB[1] = (float)aB0.y;
    accB[2] = (float)aB1.x; accB[3] = (float)aB1.y;
    accB[4] = (float)aB2.x; accB[5] = (float)aB2.y;
    accB[6] = (float)aB3.x; accB[7] = (float)aB3.y;

    #pragma unroll
    for (int j = 0; j < 8; ++j) {
        accA[j] += __shfl_xor(accA[j], 16);
        accA[j] += __shfl_xor(accA[j], 32);
        accB[j] += __shfl_xor(accB[j], 16);
        accB[j] += __shfl_xor(accB[j], 32);
    }

    if (g == 0) {
        {
            const float4 h0a = *reinterpret_cast<const float4*>(
                h0 + (size_t)rA * DD + li * 8);
            const float4 h0b = *reinterpret_cast<const float4*>(
                h0 + (size_t)rA * DD + li * 8 + 4);
            float s0 = fmaf(1.0f - ALPHA, accA[0], ALPHA * h0a.x);
            float s1 = fmaf(1.0f - ALPHA, accA[1], ALPHA * h0a.y);
            float s2 = fmaf(1.0f - ALPHA, accA[2], ALPHA * h0a.z);
            float s3 = fmaf(1.0f - ALPHA, accA[3], ALPHA * h0a.w);
            float s4 = fmaf(1.0f - ALPHA, accA[4], ALPHA * h0b.x);
            float s5 = fmaf(1.0f - ALPHA, accA[5], ALPHA * h0b.y);
            float s6 = fmaf(1.0f - ALPHA, accA[6], ALPHA * h0b.z);
            float s7 = fmaf(1.0f - ALPHA, accA[7], ALPHA * h0b.w);
            uint4 pk;
            pk.x = pkh(s0, s1);
            pk.y = pkh(s2, s3);
            pk.z = pkh(s4, s5);
            pk.w = pkh(s6, s7);
            *reinterpret_cast<uint4*>(&sA[wave * 2][li * 8]) = pk;
        }
        {
            const float4 h0a = *reinterpret_cast<const float4*>(
                h0 + (size_t)rB * DD + li * 8);
            const float4 h0b = *reinterpret_cast<const float4*>(
                h0 + (size_t)rB * DD + li * 8 + 4);
            float s0 = fmaf(1.0f - ALPHA, accB[0], ALPHA * h0a.x);
            float s1 = fmaf(1.0f - ALPHA, accB[1], ALPHA * h0a.y);
            float s2 = fmaf(1.0f - ALPHA, accB[2], ALPHA * h0a.z);
            float s3 = fmaf(1.0f - ALPHA, accB[3], ALPHA * h0a.w);
            float s4 = fmaf(1.0f - ALPHA, accB[4], ALPHA * h0b.x);
            float s5 = fmaf(1.0f - ALPHA, accB[5], ALPHA * h0b.y);
            float s6 = fmaf(1.0f - ALPHA, accB[6], ALPHA * h0b.z);
            float s7 = fmaf(1.0f - ALPHA, accB[7], ALPHA * h0b.w);
            uint4 pk;
            pk.x = pkh(s0, s1);
            pk.y = pkh(s2, s3);
            pk.z = pkh(s4, s5);
            pk.w = pkh(s6, s7);
            *reinterpret_cast<uint4*>(&sA[wave * 2 + 1][li * 8]) = pk;
        }
    }
    __syncthreads();

    // ---------------- Phase B: 8 waves, one 16-col tile each ----------------
    const int la = lane & 15;
    const int k0 = (lane >> 4) * 8;
    const int c  = wave * 16 + la;

    floatx4 facc = (floatx4){0.f, 0.f, 0.f, 0.f};

    #pragma unroll
    for (int s = 0; s < 4; ++s) {
        const int k = s * 32 + k0;
        const short8 af = *reinterpret_cast<const short8*>(&sA[la][k]);
        const short8 bf = *reinterpret_cast<const short8*>(
            wf + (size_t)c * DD + k);
        facc = __builtin_amdgcn_mfma_f32_16x16x32_f16(af, bf, facc, 0, 0, 0);
    }

    const int rg = (lane >> 4) * 4;
    const float bb = b[c];
    #pragma unroll
    for (int j = 0; j < 4; ++j) {
        const int rl = rg + j;
        const float sup = (float)(*reinterpret_cast<const _Float16*>(&sA[rl][c]));
        out[(size_t)(r0 + rl) * DD + c] =
            theta * (facc[j] + bb) + mtheta * sup;
    }
}

// ---------------------------------------------------------------------------
// Tier0 fallback (ws too small): fp32 aggregation + fp32-vector linear.
// ---------------------------------------------------------------------------
__global__ __launch_bounds__(256, 6) void agg_fp32(
    const float* __restrict__ h, const float* __restrict__ h0,
    const int* __restrict__ edge_col, const float* __restrict__ edge_vals,
    const int* __restrict__ rp, float* __restrict__ io)
{
    const int wave = threadIdx.x >> 6;
    const int lane = threadIdx.x & 63;
    const int p    = lane >> 5;
    const int li   = lane & 31;
    const int r    = blockIdx.x * 4 + wave;
    if (r >= NN) return;

    const int e0 = rp[r], e1 = rp[r + 1];

    float4 A[4];
    #pragma unroll
    for (int u = 0; u < 4; ++u) A[u] = make_float4(0.f, 0.f, 0.f, 0.f);

    for (int eb = e0; eb < e1; eb += 8) {
        #pragma unroll
        for (int u = 0; u < 4; ++u) {
            const int e  = eb + 2 * u + p;
            const int ee = min(e, e1 - 1);
            const int   c = edge_col[ee];
            const float v = (e < e1) ? edge_vals[ee] : 0.0f;
            const float4 hv =
                *reinterpret_cast<const float4*>(h + (size_t)c * DD + li * 4);
            A[u].x = fmaf(v, hv.x, A[u].x);
            A[u].y = fmaf(v, hv.y, A[u].y);
            A[u].z = fmaf(v, hv.z, A[u].z);
            A[u].w = fmaf(v, hv.w, A[u].w);
        }
    }
    float4 s;
    s.x = (A[0].x + A[1].x) + (A[2].x + A[3].x);
    s.y = (A[0].y + A[1].y) + (A[2].y + A[3].y);
    s.z = (A[0].z + A[1].z) + (A[2].z + A[3].z);
    s.w = (A[0].w + A[1].w) + (A[2].w + A[3].w);
    s.x += __shfl_xor(s.x, 32);
    s.y += __shfl_xor(s.y, 32);
    s.z += __shfl_xor(s.z, 32);
    s.w += __shfl_xor(s.w, 32);

    if (p == 0) {
        const float4 h0v =
            *reinterpret_cast<const float4*>(h0 + (size_t)r * DD + li * 4);
        float4 sup;
        sup.x = fmaf(1.0f - ALPHA, s.x, ALPHA * h0v.x);
        sup.y = fmaf(1.0f - ALPHA, s.y, ALPHA * h0v.y);
        sup.z = fmaf(1.0f - ALPHA, s.z, ALPHA * h0v.z);
        sup.w = fmaf(1.0f - ALPHA, s.w, ALPHA * h0v.w);
        *reinterpret_cast<float4*>(io + (size_t)r * DD + li * 4) = sup;
    }
}

#define RPB 64
#define SPAD 132
#define WPAD 136

__global__ __launch_bounds__(512, 4) void lin_kernel(
    float* io, const float* __restrict__ W, const float* __restrict__ b,
    const int* __restrict__ lptr)
{
    __shared__ float sS[RPB][SPAD];
    __shared__ __hip_bfloat16 sWt[DD][WPAD];

    const int tid = threadIdx.x;
    const int r0  = blockIdx.x * RPB;
    const int tr  = tid >> 4;
    const int tc  = tid & 15;

    const int lv = *lptr;
    const float theta  = logf(BETA / (float)lv + 1.0f);
    const float mtheta = 1.0f - theta;

    for (int i = tid * 4; i < DD * DD; i += 512 * 4) {
        const float4 w4 = *reinterpret_cast<const float4*>(W + i);
        const int o = i >> 7;
        const int k = i & 127;
        sWt[k + 0][o] = __float2bfloat16(w4.x);
        sWt[k + 1][o] = __float2bfloat16(w4.y);
        sWt[k + 2][o] = __float2bfloat16(w4.z);
        sWt[k + 3][o] = __float2bfloat16(w4.w);
    }

    for (int idx = tid; idx < RPB * 32; idx += 512) {
        const int row = idx >> 5;
        const int q   = idx & 31;
        const int rr  = r0 + row;
        const float4 v = (rr < NN)
            ? *reinterpret_cast<const float4*>(io + (size_t)rr * DD + q * 4)
            : make_float4(0.f, 0.f, 0.f, 0.f);
        *reinterpret_cast<float4*>(&sS[row][q * 4]) = v;
    }
    __syncthreads();

    float acc[2][8];
    #pragma unroll
    for (int i = 0; i < 2; ++i)
        #pragma unroll
        for (int j = 0; j < 8; ++j) acc[i][j] = 0.f;

    for (int k = 0; k < DD; k += 4) {
        const float4 a0 = *reinterpret_cast<const float4*>(&sS[tr * 2 + 0][k]);
        const float4 a1 = *reinterpret_cast<const float4*>(&sS[tr * 2 + 1][k]);
        const float aa0[4] = {a0.x, a0.y, a0.z, a0.w};
        const float aa1[4] = {a1.x, a1.y, a1.z, a1.w};
        #pragma unroll
        for (int kk = 0; kk < 4; ++kk) {
            const uint4 wr = *reinterpret_cast<const uint4*>(&sWt[k + kk][tc * 8]);
            float w[8];
            w[0] = bf16lo(wr.x); w[1] = bf16hi(wr.x);
            w[2] = bf16lo(wr.y); w[3] = bf16hi(wr.y);
            w[4] = bf16lo(wr.z); w[5] = bf16hi(wr.z);
            w[6] = bf16lo(wr.w); w[7] = bf16hi(wr.w);
            #pragma unroll
            for (int j = 0; j < 8; ++j) {
                acc[0][j] = fmaf(aa0[kk], w[j], acc[0][j]);
                acc[1][j] = fmaf(aa1[kk], w[j], acc[1][j]);
            }
        }
    }

    #pragma unroll
    for (int i = 0; i < 2; ++i) {
        const int ri = tr * 2 + i;
        const int rr = r0 + ri;
        if (rr >= NN) continue;
        #pragma unroll
        for (int j4 = 0; j4 < 2; ++j4) {
            const int cc = tc * 8 + j4 * 4;
            const float4 bv  = *reinterpret_cast<const float4*>(&b[cc]);
            const float4 sup = *reinterpret_cast<const float4*>(&sS[ri][cc]);
            float4 o4;
            o4.x = theta * (acc[i][j4 * 4 + 0] + bv.x) + mtheta * sup.x;
            o4.y = theta * (acc[i][j4 * 4 + 1] + bv.y) + mtheta * sup.y;
            o4.z = theta * (acc[i][j4 * 4 + 2] + bv.z) + mtheta * sup.z;
            o4.w = theta * (acc[i][j4 * 4 + 3] + bv.w) + mtheta * sup.w;
            *reinterpret_cast<float4*>(io + (size_t)rr * DD + cc) = o4;
        }
    }
}

extern "C" void kernel_launch(void* const* d_in, const int* in_sizes, int n_in,
                              void* d_out, int out_size, void* d_ws, size_t ws_size,
                              hipStream_t stream) {
    const float* h         = (const float*)d_in[0];
    const float* h0        = (const float*)d_in[1];
    const int*   edge_row  = (const int*)d_in[2];
    const int*   edge_col  = (const int*)d_in[3];
    const float* edge_vals = (const float*)d_in[4];
    const float* W         = (const float*)d_in[5];
    const float* b         = (const float*)d_in[6];
    const int*   lptr      = (const int*)d_in[7];
    const int E = in_sizes[2];

    // ws layout: rp (256KB) | hh f16 h (12.8MB) | wf f16 W (32KB)
    char* wsb = (char*)d_ws;
    const size_t sz_hh = (size_t)NN * DD * sizeof(ushort);
    const size_t sz_w  = (size_t)DD * DD * sizeof(ushort);
    int*    rp = (int*)wsb;
    ushort* hh = (ushort*)(wsb + (1 << 18));
    ushort* wf = (ushort*)(wsb + (1 << 18) + sz_hh);
    float*  io = (float*)d_out;

    const size_t need = (size_t)(1 << 18) + sz_hh + sz_w;

    const int nT = (NN * DD / 8 > E + 1) ? NN * DD / 8 : E + 1;
    const int gridP = (nT + 255) / 256;

    if (ws_size >= need) {
        prep_kernel<<<gridP, 256, 0, stream>>>(edge_row, E, rp, h, hh, W, wf);
        fused8w<<<NN / 16, 512, 0, stream>>>(
            hh, h0, edge_col, edge_vals, rp, wf, b, lptr, io);
    } else {
        prep_kernel<<<gridP, 256, 0, stream>>>(edge_row, E, rp, h,
                                               nullptr, W, nullptr);
        agg_fp32<<<(NN + 3) / 4, 256, 0, stream>>>(h, h0, edge_col, edge_vals, rp, io);
        lin_kernel<<<(NN + RPB - 1) / RPB, 512, 0, stream>>>(io, W, b, lptr);
    }
}